// Round 2
// baseline (228.674 us; speedup 1.0000x reference)
//
#include <hip/hip_runtime.h>

// WindowSlice: B=64, T=4096, C=128 fp32. L = ceil(0.9*T) = 3687.
// out[b,i,c] = lerp(x[b, s+lo(i), c], x[b, s+lo(i)+1, c], w(i))
// t = clip(i * L/(T-1), 0, L-1), lo = min(floor(t), L-2), w = t - lo.
//
// Memory-bound gather+lerp. One thread handles 2 float4 (c4 and c4+16) of one
// output row -> all loads/stores coalesced 16B/lane. XCD swizzle keeps
// adjacent output rows (which share input rows) on one XCD's L2.

constexpr int B_ = 64;
constexpr int T_ = 4096;
constexpr int L_ = 3687;          // ceil(0.9 * 4096)
constexpr int C4 = 32;            // 128 floats = 32 float4 per row
constexpr int NBLK = (B_ * T_ * (C4 / 2)) / 256;   // 16384 blocks
constexpr int NXCD = 8;
constexpr int BLK_PER_XCD = NBLK / NXCD;           // 2048

__global__ __launch_bounds__(256)
void WindowSlice_kernel(const float4* __restrict__ x,
                        const int*    __restrict__ starts,
                        float4*       __restrict__ out) {
    // XCD-aware swizzle: round-robin dispatch (xcd = blk % 8) -> give each
    // XCD a contiguous chunk of output rows so shared input rows hit its L2.
    const int lb  = (blockIdx.x & (NXCD - 1)) * BLK_PER_XCD + (blockIdx.x >> 3);
    const int wid = lb * 256 + threadIdx.x;       // work id: 2 float4 each
    const int row = wid >> 4;                     // 16 threads per row
    const int c4  = wid & 15;                     // covers c4 and c4+16
    const int b   = row >> 12;                    // / T
    const int i   = row & (T_ - 1);

    // fp32 query point (matches reference's fp32 linspace within ~ulp;
    // continuity of lerp bounds any lo off-by-one error by |slope|*ulp).
    const float step = (float)L_ / (float)(T_ - 1);
    float t = fminf((float)i * step, (float)(L_ - 1));
    int lo = (int)t;
    lo = min(lo, L_ - 2);
    const float w = t - (float)lo;

    const int start = starts[b];
    const long long base = ((long long)b * T_ + start + lo) * C4 + c4;

    const float4 a0 = x[base];
    const float4 b0 = x[base + C4];
    const float4 a1 = x[base + 16];
    const float4 b1 = x[base + C4 + 16];

    float4 o0, o1;
    o0.x = fmaf(w, b0.x - a0.x, a0.x);
    o0.y = fmaf(w, b0.y - a0.y, a0.y);
    o0.z = fmaf(w, b0.z - a0.z, a0.z);
    o0.w = fmaf(w, b0.w - a0.w, a0.w);
    o1.x = fmaf(w, b1.x - a1.x, a1.x);
    o1.y = fmaf(w, b1.y - a1.y, a1.y);
    o1.z = fmaf(w, b1.z - a1.z, a1.z);
    o1.w = fmaf(w, b1.w - a1.w, a1.w);

    const long long obase = (long long)row * C4 + c4;
    out[obase]      = o0;
    out[obase + 16] = o1;
}

extern "C" void kernel_launch(void* const* d_in, const int* in_sizes, int n_in,
                              void* d_out, int out_size, void* d_ws, size_t ws_size,
                              hipStream_t stream) {
    const float4* x      = (const float4*)d_in[0];
    const int*    starts = (const int*)d_in[1];
    float4*       out    = (float4*)d_out;

    WindowSlice_kernel<<<NBLK, 256, 0, stream>>>(x, starts, out);
}